// Round 4
// baseline (1081.873 us; speedup 1.0000x reference)
//
#include <hip/hip_runtime.h>

#define E_N   10000
#define SB_N  49
#define SBR_N 19
#define C_N   128
#define H_N   256
#define NBF_N 512
#define KPROJ 4864   // 2*SBR*C
#define NOUT  2432   // SBR*C
#define BPAD  56     // b-dim (49) padded to 56 fp16 (112 B, 16B-aligned rows)

typedef _Float16 f16x8 __attribute__((ext_vector_type(8)));
typedef _Float16 f16x4 __attribute__((ext_vector_type(4)));
typedef _Float16 f16x2 __attribute__((ext_vector_type(2)));
typedef float    f32x4 __attribute__((ext_vector_type(4)));

__device__ __forceinline__ float silu_f(float v) { return v / (1.0f + __expf(-v)); }

__device__ __forceinline__ float dot2f(f16x2 a, f16x2 b, float c) {
#if defined(__has_builtin)
#if __has_builtin(__builtin_amdgcn_fdot2)
    return __builtin_amdgcn_fdot2(a, b, c, false);
#else
    return c + (float)a[0] * (float)b[0] + (float)a[1] * (float)b[1];
#endif
#else
    return c + (float)a[0] * (float)b[0] + (float)a[1] * (float)b[1];
#endif
}

#define GLOBAL_PTR(p) ((const __attribute__((address_space(1))) void*)(p))
#define LDS_PTR(p)    ((__attribute__((address_space(3))) void*)(p))

// ---------------------------------------------------------------------------
// Tiled transpose + fp32->fp16: out[n*K + k] = (f16) in[k*N + n]
// ---------------------------------------------------------------------------
__launch_bounds__(256)
__global__ void transpose_to_f16(const float* __restrict__ in, _Float16* __restrict__ out,
                                 int K, int N)
{
    __shared__ float tile[32][33];
    const int k0 = blockIdx.x * 32;
    const int n0 = blockIdx.y * 32;
    const int tx = threadIdx.x & 31;
    const int ty = threadIdx.x >> 5;
    #pragma unroll
    for (int i = ty; i < 32; i += 8)
        if (k0 + i < K && n0 + tx < N)
            tile[i][tx] = in[(size_t)(k0 + i) * N + (n0 + tx)];
    __syncthreads();
    #pragma unroll
    for (int i = ty; i < 32; i += 8)
        if (n0 + i < N && k0 + tx < K)
            out[(size_t)(n0 + i) * K + (k0 + tx)] = (_Float16)tile[tx][i];
}

// ---------------------------------------------------------------------------
// fp32 -> fp16 bulk convert
// ---------------------------------------------------------------------------
__launch_bounds__(256)
__global__ void cvt_to_f16(const float* __restrict__ in, _Float16* __restrict__ out, int n4)
{
    int i = blockIdx.x * blockDim.x + threadIdx.x;
    const int stride = gridDim.x * blockDim.x;
    for (; i < n4; i += stride) {
        const float4 v = ((const float4*)in)[i];
        f16x4 o; o[0] = (_Float16)v.x; o[1] = (_Float16)v.y; o[2] = (_Float16)v.z; o[3] = (_Float16)v.w;
        ((f16x4*)out)[i] = o;
    }
}

// ---------------------------------------------------------------------------
// Prep: xt[n][c][b] = (f16) x[n][b][c], b padded to BPAD=56 with zeros.
// ---------------------------------------------------------------------------
__launch_bounds__(256)
__global__ void prep_xt(const float* __restrict__ x, _Float16* __restrict__ xt)
{
    __shared__ float xs[SB_N * C_N];
    __shared__ _Float16 xl[C_N * BPAD];
    const int n = blockIdx.x;
    const int tid = threadIdx.x;
    for (int t = tid; t < (SB_N * C_N) / 4; t += 256)
        ((float4*)xs)[t] = ((const float4*)(x + (size_t)n * (SB_N * C_N)))[t];
    __syncthreads();
    for (int t = tid; t < C_N * (BPAD / 2); t += 256) {
        const int c = t & 127;
        const int j = t >> 7;
        const int b0 = 2 * j, b1 = 2 * j + 1;
        f16x2 p;
        p[0] = (b0 < SB_N) ? (_Float16)xs[b0 * C_N + c] : (_Float16)0.f;
        p[1] = (b1 < SB_N) ? (_Float16)xs[b1 * C_N + c] : (_Float16)0.f;
        ((f16x2*)xl)[c * (BPAD / 2) + j] = p;
    }
    __syncthreads();
    _Float16* dst = xt + (size_t)n * (C_N * BPAD);
    for (int t = tid; t < (C_N * BPAD) / 4; t += 256)
        ((f16x4*)dst)[t] = ((const f16x4*)xl)[t];
}

// ---------------------------------------------------------------------------
// MFMA GEMM v2: C[M,N](f16) = silu(A[M,K](f16) @ BT[N,K]^T + bias[N]) [* gate]
// 64x64 tile, BK=64, 4 waves (2x2, each 32x32), double-buffered LDS with
// 2-phase schedule (STAGE next before compute of current, one drain/tile).
// 1D grid nbn*nbm with bijective XCD-chunked swizzle so the nbn consecutive
// tiles sharing an A-panel land on the same XCD's L2.
// Requires K % 128 == 0 (nt even), N % 64 == 0. M ragged (pad rows readable).
// ---------------------------------------------------------------------------
template<int GATED>
__launch_bounds__(256, 4)
__global__ void gemm_f16(const _Float16* __restrict__ A, int lda,
                         const _Float16* __restrict__ BT,
                         const float* __restrict__ bias,
                         const _Float16* __restrict__ gate,
                         _Float16* __restrict__ C,
                         int M, int N, int K, int i0)
{
    __shared__ __align__(16) _Float16 As[2][8][64][8];   // [buf][kslot][row][8]
    __shared__ __align__(16) _Float16 Bs[2][8][64][8];
    const int tid  = threadIdx.x;
    const int lane = tid & 63;
    const int w    = tid >> 6;
    const int wr   = w >> 1;
    const int wc   = w & 1;

    // XCD-chunked bijective swizzle (m204): consecutive logical g -> same XCD
    const unsigned nwg = gridDim.x;
    const unsigned q = nwg >> 3, r = nwg & 7;
    const unsigned xcd = blockIdx.x & 7, lo = blockIdx.x >> 3;
    const unsigned g = (xcd < r ? xcd * (q + 1) : r * (q + 1) + (xcd - r) * q) + lo;
    const int nbn = N >> 6;
    const int n0 = (int)(g % (unsigned)nbn) * 64;
    const int m0 = (int)(g / (unsigned)nbn) * 64;

    // staging: chunk j in {0,1}: lin = j*256 + tid (16B units); kslot = lin>>6, row = lin&63
    const int rs = tid & 63;
    const int ks = tid >> 6;                 // 0..3 (j=1 adds 4)
    const _Float16* ag = A  + (size_t)(m0 + rs) * lda + ks * 8;
    const _Float16* bg = BT + (size_t)(n0 + rs) * K   + ks * 8;
    _Float16* sa0 = &As[0][0][0][0] + tid * 8;
    _Float16* sa1 = &As[1][0][0][0] + tid * 8;
    _Float16* sb0 = &Bs[0][0][0][0] + tid * 8;
    _Float16* sb1 = &Bs[1][0][0][0] + tid * 8;

    const int frow = lane & 15;
    const int fks  = lane >> 4;              // k-group within 32
    const _Float16* fA0 = &As[0][fks][wr * 32 + frow][0];
    const _Float16* fA1 = &As[1][fks][wr * 32 + frow][0];
    const _Float16* fB0 = &Bs[0][fks][wc * 32 + frow][0];
    const _Float16* fB1 = &Bs[1][fks][wc * 32 + frow][0];

    f32x4 acc[2][2] = {};

#define STAGE(SA, SB, KOFF) do {                                                          \
    __builtin_amdgcn_global_load_lds(GLOBAL_PTR(ag + (KOFF)),      LDS_PTR(SA),        16, 0, 0); \
    __builtin_amdgcn_global_load_lds(GLOBAL_PTR(ag + (KOFF) + 32), LDS_PTR(SA + 2048), 16, 0, 0); \
    __builtin_amdgcn_global_load_lds(GLOBAL_PTR(bg + (KOFF)),      LDS_PTR(SB),        16, 0, 0); \
    __builtin_amdgcn_global_load_lds(GLOBAL_PTR(bg + (KOFF) + 32), LDS_PTR(SB + 2048), 16, 0, 0); \
} while (0)

#define COMPUTE(FA, FB) do {                                                   \
    const f16x8 a0m0 = *(const f16x8*)(FA);                                    \
    const f16x8 a0m1 = *(const f16x8*)(FA + 128);                              \
    const f16x8 a1m0 = *(const f16x8*)(FA + 2048);                             \
    const f16x8 a1m1 = *(const f16x8*)(FA + 2048 + 128);                       \
    const f16x8 b0n0 = *(const f16x8*)(FB);                                    \
    const f16x8 b0n1 = *(const f16x8*)(FB + 128);                              \
    const f16x8 b1n0 = *(const f16x8*)(FB + 2048);                             \
    const f16x8 b1n1 = *(const f16x8*)(FB + 2048 + 128);                       \
    acc[0][0] = __builtin_amdgcn_mfma_f32_16x16x32_f16(a0m0, b0n0, acc[0][0], 0, 0, 0); \
    acc[0][1] = __builtin_amdgcn_mfma_f32_16x16x32_f16(a0m0, b0n1, acc[0][1], 0, 0, 0); \
    acc[1][0] = __builtin_amdgcn_mfma_f32_16x16x32_f16(a0m1, b0n0, acc[1][0], 0, 0, 0); \
    acc[1][1] = __builtin_amdgcn_mfma_f32_16x16x32_f16(a0m1, b0n1, acc[1][1], 0, 0, 0); \
    acc[0][0] = __builtin_amdgcn_mfma_f32_16x16x32_f16(a1m0, b1n0, acc[0][0], 0, 0, 0); \
    acc[0][1] = __builtin_amdgcn_mfma_f32_16x16x32_f16(a1m0, b1n1, acc[0][1], 0, 0, 0); \
    acc[1][0] = __builtin_amdgcn_mfma_f32_16x16x32_f16(a1m1, b1n0, acc[1][0], 0, 0, 0); \
    acc[1][1] = __builtin_amdgcn_mfma_f32_16x16x32_f16(a1m1, b1n1, acc[1][1], 0, 0, 0); \
} while (0)

    const int nt = K >> 6;                   // even for all our K
    STAGE(sa0, sb0, 0);
    __syncthreads();                         // buf0 ready
    int koff = 64;
    for (int t = 0; t + 2 <= nt; t += 2) {
        STAGE(sa1, sb1, koff); koff += 64;   // prefetch t+1 into buf1
        COMPUTE(fA0, fB0);
        __syncthreads();                     // drain: buf1 ready, buf0 free
        if (t + 2 < nt) { STAGE(sa0, sb0, koff); koff += 64; }
        COMPUTE(fA1, fB1);
        __syncthreads();
    }
#undef STAGE
#undef COMPUTE

    #pragma unroll
    for (int m = 0; m < 2; ++m) {
        #pragma unroll
        for (int n = 0; n < 2; ++n) {
            const int gn = n0 + wc * 32 + n * 16 + (lane & 15);
            #pragma unroll
            for (int rr = 0; rr < 4; ++rr) {
                const int gm = m0 + wr * 32 + m * 16 + (lane >> 4) * 4 + rr;
                if (gm < M) {
                    float v = acc[m][n][rr] + bias[gn];
                    v = silu_f(v);
                    if (GATED) v *= (float)gate[(size_t)((i0 + gm) >> 1) * H_N + gn];
                    C[(size_t)gm * N + gn] = (_Float16)v;
                }
            }
        }
    }
}

// ---------------------------------------------------------------------------
// Rotate v2: one block per EDGE (both y, both parts).
// ---------------------------------------------------------------------------
__launch_bounds__(256)
__global__ void rotate_v2(const _Float16* __restrict__ xt, const float* __restrict__ wigner,
                          const int* __restrict__ eidx, _Float16* __restrict__ rot, int e0)
{
    __shared__ __align__(16) _Float16 xs_t[2][C_N * BPAD];
    __shared__ __align__(16) _Float16 wg[2][SBR_N * BPAD];
    const int tid = threadIdx.x;
    const int e = e0 + blockIdx.x;
    const int node0 = eidx[0 * E_N + e];
    const int node1 = eidx[1 * E_N + e];

    const f16x8* s0 = (const f16x8*)(xt + (size_t)node0 * (C_N * BPAD));
    const f16x8* s1 = (const f16x8*)(xt + (size_t)node1 * (C_N * BPAD));
    for (int t = tid; t < (C_N * BPAD) / 8; t += 256) {
        *(f16x8*)&xs_t[0][t * 8] = s0[t];
        *(f16x8*)&xs_t[1][t * 8] = s1[t];
    }
    for (int t = tid; t < 2 * SBR_N * SB_N; t += 256) {
        const int y = t / (SBR_N * SB_N);
        const int sb = t - y * (SBR_N * SB_N);
        const int s = sb / SB_N, b = sb - s * SB_N;
        wg[y][s * BPAD + b] = (_Float16)wigner[((size_t)(2 * e) + y) * (SBR_N * SB_N) + sb];
    }
    for (int t = tid; t < 2 * SBR_N * (BPAD - SB_N); t += 256) {
        const int y = t / (SBR_N * (BPAD - SB_N));
        const int rr = t - y * (SBR_N * (BPAD - SB_N));
        const int s = rr / (BPAD - SB_N), j = rr - s * (BPAD - SB_N);
        wg[y][s * BPAD + SB_N + j] = (_Float16)0.f;
    }
    __syncthreads();

    const int c = tid & 127;
    const int part = tid >> 7;

    f16x2 xc[BPAD / 2];
    const f16x2* xr = (const f16x2*)&xs_t[part][c * BPAD];
    #pragma unroll
    for (int j = 0; j < BPAD / 2; ++j) xc[j] = xr[j];

    const size_t rowbase = 2 * (size_t)blockIdx.x;
    #pragma unroll
    for (int y = 0; y < 2; ++y) {
        _Float16* orow = rot + (rowbase + y) * KPROJ + part * NOUT + c;
        for (int s = 0; s < SBR_N; ++s) {
            const f16x2* wrp = (const f16x2*)&wg[y][s * BPAD];
            float acc = 0.f;
            #pragma unroll
            for (int j = 0; j < BPAD / 2; ++j)
                acc = dot2f(xc[j], wrp[j], acc);
            orow[s * C_N] = (_Float16)acc;
        }
    }
}

// ---------------------------------------------------------------------------
// Combine: out[e,b,c] = sum_s wigner_inv[e,b,s] * 0.5*(h3[2eb,s,c] + h3[2eb+1,s,c])
// ---------------------------------------------------------------------------
__launch_bounds__(128)
__global__ void combine_kernel(const _Float16* __restrict__ h3, const float* __restrict__ wigner_inv,
                               float* __restrict__ out, int e0)
{
    __shared__ float ms[SBR_N * C_N];
    __shared__ float wv[SB_N * SBR_N];
    const int eb = blockIdx.x;
    const int e = e0 + eb;
    const int c = threadIdx.x;

    #pragma unroll
    for (int s = 0; s < SBR_N; ++s) {
        const float a = (float)h3[(size_t)(2 * eb) * NOUT + s * C_N + c];
        const float b = (float)h3[(size_t)(2 * eb + 1) * NOUT + s * C_N + c];
        ms[s * C_N + c] = 0.5f * (a + b);
    }
    for (int t = c; t < SB_N * SBR_N; t += 128)
        wv[t] = wigner_inv[(size_t)e * (SB_N * SBR_N) + t];
    __syncthreads();

    for (int b = 0; b < SB_N; ++b) {
        float acc = 0.f;
        #pragma unroll
        for (int s = 0; s < SBR_N; ++s)
            acc += wv[b * SBR_N + s] * ms[s * C_N + c];
        out[(size_t)e * (SB_N * C_N) + b * C_N + c] = acc;
    }
}

// ---------------------------------------------------------------------------
extern "C" void kernel_launch(void* const* d_in, const int* in_sizes, int n_in,
                              void* d_out, int out_size, void* d_ws, size_t ws_size,
                              hipStream_t stream)
{
    const float* x          = (const float*)d_in[0];
    const float* x_edge     = (const float*)d_in[1];
    const int*   eidx       = (const int*)d_in[2];
    const float* wigner     = (const float*)d_in[3];
    const float* wigner_inv = (const float*)d_in[4];
    const float* w_dist     = (const float*)d_in[5];
    const float* b_dist     = (const float*)d_in[6];
    const float* w_proj     = (const float*)d_in[7];
    const float* b_proj     = (const float*)d_in[8];
    const float* w_edge     = (const float*)d_in[9];
    const float* b_edge     = (const float*)d_in[10];
    const float* w_out      = (const float*)d_in[11];
    const float* b_out      = (const float*)d_in[12];
    float* out = (float*)d_out;

    // ---- workspace layout ----
    char* wsp = (char*)d_ws;
    auto alloc = [&](size_t bytes) -> char* {
        char* p = wsp;
        wsp += (bytes + 255) & ~(size_t)255;
        return p;
    };
    const int XE_ROWS = 10112;                       // 158*64, padded for staging reads
    _Float16* gate = (_Float16*)alloc((size_t)E_N * H_N * sizeof(_Float16));
    _Float16* wTd  = (_Float16*)alloc((size_t)H_N * NBF_N * sizeof(_Float16));
    _Float16* wTp  = (_Float16*)alloc((size_t)H_N * KPROJ * sizeof(_Float16));
    _Float16* wTe  = (_Float16*)alloc((size_t)H_N * H_N * sizeof(_Float16));
    _Float16* wTo  = (_Float16*)alloc((size_t)NOUT * H_N * sizeof(_Float16));
    _Float16* xeh  = (_Float16*)alloc((size_t)XE_ROWS * NBF_N * sizeof(_Float16));
    _Float16* xt   = (_Float16*)alloc((size_t)5000 * C_N * BPAD * sizeof(_Float16)); // 71.7 MB

    const size_t used = (size_t)(wsp - (char*)d_ws);
    const size_t avail = ws_size > used ? ws_size - used : 0;
    const size_t per_row = (size_t)(KPROJ + H_N + H_N) * sizeof(_Float16);   // 10752 B
    long cimax = (long)(avail / per_row) & ~127L;    // multiple of 128 (even, /64)
    if (cimax > 20096) cimax = 20096;
    if (cimax < 128) cimax = 128;

    _Float16* rot = (_Float16*)alloc((size_t)cimax * KPROJ * sizeof(_Float16)); // reused as h3
    _Float16* h1  = (_Float16*)alloc((size_t)cimax * H_N * sizeof(_Float16));
    _Float16* h2  = (_Float16*)alloc((size_t)cimax * H_N * sizeof(_Float16));

    // ---- one-time prep ----
    transpose_to_f16<<<dim3(NBF_N / 32, H_N / 32), 256, 0, stream>>>(w_dist, wTd, NBF_N, H_N);
    transpose_to_f16<<<dim3(KPROJ / 32, H_N / 32), 256, 0, stream>>>(w_proj, wTp, KPROJ, H_N);
    transpose_to_f16<<<dim3(H_N / 32, H_N / 32), 256, 0, stream>>>(w_edge, wTe, H_N, H_N);
    transpose_to_f16<<<dim3(H_N / 32, NOUT / 32), 256, 0, stream>>>(w_out, wTo, H_N, NOUT);
    cvt_to_f16<<<dim3(1024), 256, 0, stream>>>(x_edge, xeh, (E_N * NBF_N) / 4);
    prep_xt<<<dim3(5000), 256, 0, stream>>>(x, xt);

    // 1. gate[e,h] = silu(x_edge @ w_dist + b_dist), fp16 out
    gemm_f16<0><<<dim3((H_N / 64) * (XE_ROWS / 64)), 256, 0, stream>>>(
        xeh, NBF_N, wTd, b_dist, nullptr, gate, E_N, H_N, NBF_N, 0);

    for (long i0 = 0; i0 < 2L * E_N; i0 += cimax) {
        long ci = 2L * E_N - i0;
        if (ci > cimax) ci = cimax;
        const unsigned mb = (unsigned)((ci + 63) / 64);

        // 2. rotate source+target into rot[ci, 4864] (fp16), one block per edge
        rotate_v2<<<dim3((unsigned)(ci / 2)), 256, 0, stream>>>(
            xt, wigner, eidx, rot, (int)(i0 / 2));

        // 3. h1 = silu(rot @ w_proj + b_proj) * gate[e]
        gemm_f16<1><<<dim3((H_N / 64) * mb), 256, 0, stream>>>(
            rot, KPROJ, wTp, b_proj, gate, h1, (int)ci, H_N, KPROJ, (int)i0);

        // 4. h2 = silu(h1 @ w_edge + b_edge)
        gemm_f16<0><<<dim3((H_N / 64) * mb), 256, 0, stream>>>(
            h1, H_N, wTe, b_edge, nullptr, h2, (int)ci, H_N, H_N, 0);

        // 5. h3 = silu(h2 @ w_out + b_out)   (reuses rot buffer)
        gemm_f16<0><<<dim3((NOUT / 64) * mb), 256, 0, stream>>>(
            h2, H_N, wTo, b_out, nullptr, rot, (int)ci, NOUT, H_N, 0);

        // 6. out[e] = wigner_inv[e] @ mean_Y(h3)
        combine_kernel<<<dim3((unsigned)(ci / 2)), 128, 0, stream>>>(
            rot, wigner_inv, out, (int)(i0 / 2));
    }
}

// Round 5
// 995.711 us; speedup vs baseline: 1.0865x; 1.0865x over previous
//
#include <hip/hip_runtime.h>

#define E_N   10000
#define SB_N  49
#define SBR_N 19
#define C_N   128
#define H_N   256
#define NBF_N 512
#define KPROJ 4864   // 2*SBR*C
#define NOUT  2432   // SBR*C
#define BPAD  56     // b-dim (49) padded to 56 fp16 (112 B, 16B-aligned rows)
#define KSPLIT 4
#define KCH   (KPROJ / KSPLIT)   // 1216, 38 BK=32 steps

typedef _Float16 f16x8 __attribute__((ext_vector_type(8)));
typedef _Float16 f16x4 __attribute__((ext_vector_type(4)));
typedef _Float16 f16x2 __attribute__((ext_vector_type(2)));
typedef float    f32x4 __attribute__((ext_vector_type(4)));

__device__ __forceinline__ float silu_f(float v) { return v / (1.0f + __expf(-v)); }

__device__ __forceinline__ float dot2f(f16x2 a, f16x2 b, float c) {
#if defined(__has_builtin)
#if __has_builtin(__builtin_amdgcn_fdot2)
    return __builtin_amdgcn_fdot2(a, b, c, false);
#else
    return c + (float)a[0] * (float)b[0] + (float)a[1] * (float)b[1];
#endif
#else
    return c + (float)a[0] * (float)b[0] + (float)a[1] * (float)b[1];
#endif
}

#define GLOBAL_PTR(p) ((const __attribute__((address_space(1))) void*)(p))
#define LDS_PTR(p)    ((__attribute__((address_space(3))) void*)(p))

// ---------------------------------------------------------------------------
// Tiled transpose + fp32->fp16: out[n*K + k] = (f16) in[k*N + n]
// ---------------------------------------------------------------------------
__launch_bounds__(256)
__global__ void transpose_to_f16(const float* __restrict__ in, _Float16* __restrict__ out,
                                 int K, int N)
{
    __shared__ float tile[32][33];
    const int k0 = blockIdx.x * 32;
    const int n0 = blockIdx.y * 32;
    const int tx = threadIdx.x & 31;
    const int ty = threadIdx.x >> 5;
    #pragma unroll
    for (int i = ty; i < 32; i += 8)
        if (k0 + i < K && n0 + tx < N)
            tile[i][tx] = in[(size_t)(k0 + i) * N + (n0 + tx)];
    __syncthreads();
    #pragma unroll
    for (int i = ty; i < 32; i += 8)
        if (n0 + i < N && k0 + tx < K)
            out[(size_t)(n0 + i) * K + (k0 + tx)] = (_Float16)tile[tx][i];
}

// ---------------------------------------------------------------------------
// fp32 -> fp16 bulk convert
// ---------------------------------------------------------------------------
__launch_bounds__(256)
__global__ void cvt_to_f16(const float* __restrict__ in, _Float16* __restrict__ out, int n4)
{
    int i = blockIdx.x * blockDim.x + threadIdx.x;
    const int stride = gridDim.x * blockDim.x;
    for (; i < n4; i += stride) {
        const float4 v = ((const float4*)in)[i];
        f16x4 o; o[0] = (_Float16)v.x; o[1] = (_Float16)v.y; o[2] = (_Float16)v.z; o[3] = (_Float16)v.w;
        ((f16x4*)out)[i] = o;
    }
}

// ---------------------------------------------------------------------------
// Prep: xt[n][c][b] = (f16) x[n][b][c], b padded to BPAD=56 with zeros.
// ---------------------------------------------------------------------------
__launch_bounds__(256)
__global__ void prep_xt(const float* __restrict__ x, _Float16* __restrict__ xt)
{
    __shared__ float xs[SB_N * C_N];
    __shared__ _Float16 xl[C_N * BPAD];
    const int n = blockIdx.x;
    const int tid = threadIdx.x;
    for (int t = tid; t < (SB_N * C_N) / 4; t += 256)
        ((float4*)xs)[t] = ((const float4*)(x + (size_t)n * (SB_N * C_N)))[t];
    __syncthreads();
    for (int t = tid; t < C_N * (BPAD / 2); t += 256) {
        const int c = t & 127;
        const int j = t >> 7;
        const int b0 = 2 * j, b1 = 2 * j + 1;
        f16x2 p;
        p[0] = (b0 < SB_N) ? (_Float16)xs[b0 * C_N + c] : (_Float16)0.f;
        p[1] = (b1 < SB_N) ? (_Float16)xs[b1 * C_N + c] : (_Float16)0.f;
        ((f16x2*)xl)[c * (BPAD / 2) + j] = p;
    }
    __syncthreads();
    _Float16* dst = xt + (size_t)n * (C_N * BPAD);
    for (int t = tid; t < (C_N * BPAD) / 4; t += 256)
        ((f16x4*)dst)[t] = ((const f16x4*)xl)[t];
}

// ---------------------------------------------------------------------------
// MFMA GEMM (round-2 structure): C[M,N](f16) = silu(A@BT^T + bias) [* gate]
// BM=BN=128, BK=32, 256 threads = 4 waves (2x2), 4x4 16x16x32 frags per wave.
// grid: (N/128, ceil(M/128)).
// ---------------------------------------------------------------------------
template<int GATED>
__launch_bounds__(256, 2)
__global__ void gemm_f16(const _Float16* __restrict__ A, int lda,
                         const _Float16* __restrict__ BT,
                         const float* __restrict__ bias,
                         const _Float16* __restrict__ gate,
                         _Float16* __restrict__ C,
                         int M, int N, int K, int i0)
{
    __shared__ __align__(16) _Float16 As[4][128][8];
    __shared__ __align__(16) _Float16 Bs[4][128][8];
    const int tid  = threadIdx.x;
    const int lane = tid & 63;
    const int w    = tid >> 6;
    const int wr   = w >> 1;
    const int wc   = w & 1;
    const int n0   = blockIdx.x * 128;
    const int m0   = blockIdx.y * 128;

    const int r01 = tid & 127;
    const int ks0 = tid >> 7;
    const int ks1 = ks0 + 2;
    const _Float16* a0 = A  + (size_t)(m0 + r01) * lda + ks0 * 8;
    const _Float16* a1 = A  + (size_t)(m0 + r01) * lda + ks1 * 8;
    const _Float16* b0 = BT + (size_t)(n0 + r01) * K   + ks0 * 8;
    const _Float16* b1 = BT + (size_t)(n0 + r01) * K   + ks1 * 8;
    _Float16* sA0 = &As[0][0][0] + (size_t)tid * 8;
    _Float16* sA1 = sA0 + 2048;
    _Float16* sB0 = &Bs[0][0][0] + (size_t)tid * 8;
    _Float16* sB1 = sB0 + 2048;

    const int frow = lane & 15;
    const int fks  = lane >> 4;
    const _Float16* fA = &As[fks][wr * 64 + frow][0];
    const _Float16* fB = &Bs[fks][wc * 64 + frow][0];

    f32x4 acc[4][4] = {};

    for (int k0 = 0; k0 < K; k0 += 32) {
        __builtin_amdgcn_global_load_lds(GLOBAL_PTR(a0 + k0), LDS_PTR(sA0), 16, 0, 0);
        __builtin_amdgcn_global_load_lds(GLOBAL_PTR(a1 + k0), LDS_PTR(sA1), 16, 0, 0);
        __builtin_amdgcn_global_load_lds(GLOBAL_PTR(b0 + k0), LDS_PTR(sB0), 16, 0, 0);
        __builtin_amdgcn_global_load_lds(GLOBAL_PTR(b1 + k0), LDS_PTR(sB1), 16, 0, 0);
        __syncthreads();
        f16x8 af[4], bf[4];
        #pragma unroll
        for (int m = 0; m < 4; ++m) af[m] = *(const f16x8*)(fA + m * 16 * 8);
        #pragma unroll
        for (int n = 0; n < 4; ++n) bf[n] = *(const f16x8*)(fB + n * 16 * 8);
        #pragma unroll
        for (int m = 0; m < 4; ++m)
            #pragma unroll
            for (int n = 0; n < 4; ++n)
                acc[m][n] = __builtin_amdgcn_mfma_f32_16x16x32_f16(af[m], bf[n], acc[m][n], 0, 0, 0);
        __syncthreads();
    }

    #pragma unroll
    for (int m = 0; m < 4; ++m) {
        #pragma unroll
        for (int n = 0; n < 4; ++n) {
            const int gn = n0 + wc * 64 + n * 16 + (lane & 15);
            #pragma unroll
            for (int r = 0; r < 4; ++r) {
                const int gm = m0 + wr * 64 + m * 16 + (lane >> 4) * 4 + r;
                if (gm < M) {
                    float v = acc[m][n][r] + bias[gn];
                    v = silu_f(v);
                    if (GATED) v *= (float)gate[(size_t)((i0 + gm) >> 1) * H_N + gn];
                    C[(size_t)gm * N + gn] = (_Float16)v;
                }
            }
        }
    }
}

// ---------------------------------------------------------------------------
// Split-K MFMA GEMM for proj: partial[ks][m][n] = A[m, ks*KCH : (ks+1)*KCH] @ BT^T
// Same 128x128/BK=32 structure; raw f32 output, no epilogue.
// grid: (N/128, ceil(M/128), KSPLIT). pstride = row-capacity * H_N.
// ---------------------------------------------------------------------------
__launch_bounds__(256, 2)
__global__ void gemm_f16_splitk(const _Float16* __restrict__ A, int lda,
                                const _Float16* __restrict__ BT,
                                float* __restrict__ partial, size_t pstride,
                                int N)
{
    __shared__ __align__(16) _Float16 As[4][128][8];
    __shared__ __align__(16) _Float16 Bs[4][128][8];
    const int tid  = threadIdx.x;
    const int lane = tid & 63;
    const int w    = tid >> 6;
    const int wr   = w >> 1;
    const int wc   = w & 1;
    const int n0   = blockIdx.x * 128;
    const int m0   = blockIdx.y * 128;
    const int kspl = blockIdx.z;

    const int r01 = tid & 127;
    const int ks0 = tid >> 7;
    const int ks1 = ks0 + 2;
    const _Float16* a0 = A  + (size_t)(m0 + r01) * lda + kspl * KCH + ks0 * 8;
    const _Float16* a1 = A  + (size_t)(m0 + r01) * lda + kspl * KCH + ks1 * 8;
    const _Float16* b0 = BT + (size_t)(n0 + r01) * KPROJ + kspl * KCH + ks0 * 8;
    const _Float16* b1 = BT + (size_t)(n0 + r01) * KPROJ + kspl * KCH + ks1 * 8;
    _Float16* sA0 = &As[0][0][0] + (size_t)tid * 8;
    _Float16* sA1 = sA0 + 2048;
    _Float16* sB0 = &Bs[0][0][0] + (size_t)tid * 8;
    _Float16* sB1 = sB0 + 2048;

    const int frow = lane & 15;
    const int fks  = lane >> 4;
    const _Float16* fA = &As[fks][wr * 64 + frow][0];
    const _Float16* fB = &Bs[fks][wc * 64 + frow][0];

    f32x4 acc[4][4] = {};

    for (int k0 = 0; k0 < KCH; k0 += 32) {
        __builtin_amdgcn_global_load_lds(GLOBAL_PTR(a0 + k0), LDS_PTR(sA0), 16, 0, 0);
        __builtin_amdgcn_global_load_lds(GLOBAL_PTR(a1 + k0), LDS_PTR(sA1), 16, 0, 0);
        __builtin_amdgcn_global_load_lds(GLOBAL_PTR(b0 + k0), LDS_PTR(sB0), 16, 0, 0);
        __builtin_amdgcn_global_load_lds(GLOBAL_PTR(b1 + k0), LDS_PTR(sB1), 16, 0, 0);
        __syncthreads();
        f16x8 af[4], bf[4];
        #pragma unroll
        for (int m = 0; m < 4; ++m) af[m] = *(const f16x8*)(fA + m * 16 * 8);
        #pragma unroll
        for (int n = 0; n < 4; ++n) bf[n] = *(const f16x8*)(fB + n * 16 * 8);
        #pragma unroll
        for (int m = 0; m < 4; ++m)
            #pragma unroll
            for (int n = 0; n < 4; ++n)
                acc[m][n] = __builtin_amdgcn_mfma_f32_16x16x32_f16(af[m], bf[n], acc[m][n], 0, 0, 0);
        __syncthreads();
    }

    float* pout = partial + (size_t)kspl * pstride;
    #pragma unroll
    for (int m = 0; m < 4; ++m) {
        #pragma unroll
        for (int n = 0; n < 4; ++n) {
            const int gn = n0 + wc * 64 + n * 16 + (lane & 15);
            #pragma unroll
            for (int r = 0; r < 4; ++r) {
                const int gm = m0 + wr * 64 + m * 16 + (lane >> 4) * 4 + r;
                pout[(size_t)gm * N + gn] = acc[m][n][r];
            }
        }
    }
}

// ---------------------------------------------------------------------------
// Reduce split-K partials: h1[m,n] = silu(sum_ks partial + bias[n]) * gate
// Each thread: one float4-group of n. Grid-stride.
// ---------------------------------------------------------------------------
__launch_bounds__(256)
__global__ void reduce_silu_gate(const float* __restrict__ partial, size_t pstride,
                                 const float* __restrict__ bias,
                                 const _Float16* __restrict__ gate,
                                 _Float16* __restrict__ h1, int ci, int i0)
{
    const int total = ci * (H_N / 4);
    const int gstride = gridDim.x * blockDim.x;
    for (int idx = blockIdx.x * blockDim.x + threadIdx.x; idx < total; idx += gstride) {
        const int m = idx >> 6;
        const int n = (idx & 63) * 4;
        const size_t off = (size_t)m * H_N + n;
        const float4 p0 = *(const float4*)(partial + 0 * pstride + off);
        const float4 p1 = *(const float4*)(partial + 1 * pstride + off);
        const float4 p2 = *(const float4*)(partial + 2 * pstride + off);
        const float4 p3 = *(const float4*)(partial + 3 * pstride + off);
        const float4 bi = *(const float4*)(bias + n);
        const f16x4 g = *(const f16x4*)(gate + (size_t)((i0 + m) >> 1) * H_N + n);
        f16x4 o;
        float v;
        v = p0.x + p1.x + p2.x + p3.x + bi.x; v = silu_f(v) * (float)g[0]; o[0] = (_Float16)v;
        v = p0.y + p1.y + p2.y + p3.y + bi.y; v = silu_f(v) * (float)g[1]; o[1] = (_Float16)v;
        v = p0.z + p1.z + p2.z + p3.z + bi.z; v = silu_f(v) * (float)g[2]; o[2] = (_Float16)v;
        v = p0.w + p1.w + p2.w + p3.w + bi.w; v = silu_f(v) * (float)g[3]; o[3] = (_Float16)v;
        *(f16x4*)(h1 + off) = o;
    }
}

// ---------------------------------------------------------------------------
// Rotate v2: one block per EDGE (both y, both parts).
// ---------------------------------------------------------------------------
__launch_bounds__(256)
__global__ void rotate_v2(const _Float16* __restrict__ xt, const float* __restrict__ wigner,
                          const int* __restrict__ eidx, _Float16* __restrict__ rot, int e0)
{
    __shared__ __align__(16) _Float16 xs_t[2][C_N * BPAD];
    __shared__ __align__(16) _Float16 wg[2][SBR_N * BPAD];
    const int tid = threadIdx.x;
    const int e = e0 + blockIdx.x;
    const int node0 = eidx[0 * E_N + e];
    const int node1 = eidx[1 * E_N + e];

    const f16x8* s0 = (const f16x8*)(xt + (size_t)node0 * (C_N * BPAD));
    const f16x8* s1 = (const f16x8*)(xt + (size_t)node1 * (C_N * BPAD));
    for (int t = tid; t < (C_N * BPAD) / 8; t += 256) {
        *(f16x8*)&xs_t[0][t * 8] = s0[t];
        *(f16x8*)&xs_t[1][t * 8] = s1[t];
    }
    for (int t = tid; t < 2 * SBR_N * SB_N; t += 256) {
        const int y = t / (SBR_N * SB_N);
        const int sb = t - y * (SBR_N * SB_N);
        const int s = sb / SB_N, b = sb - s * SB_N;
        wg[y][s * BPAD + b] = (_Float16)wigner[((size_t)(2 * e) + y) * (SBR_N * SB_N) + sb];
    }
    for (int t = tid; t < 2 * SBR_N * (BPAD - SB_N); t += 256) {
        const int y = t / (SBR_N * (BPAD - SB_N));
        const int rr = t - y * (SBR_N * (BPAD - SB_N));
        const int s = rr / (BPAD - SB_N), j = rr - s * (BPAD - SB_N);
        wg[y][s * BPAD + SB_N + j] = (_Float16)0.f;
    }
    __syncthreads();

    const int c = tid & 127;
    const int part = tid >> 7;

    f16x2 xc[BPAD / 2];
    const f16x2* xr = (const f16x2*)&xs_t[part][c * BPAD];
    #pragma unroll
    for (int j = 0; j < BPAD / 2; ++j) xc[j] = xr[j];

    const size_t rowbase = 2 * (size_t)blockIdx.x;
    #pragma unroll
    for (int y = 0; y < 2; ++y) {
        _Float16* orow = rot + (rowbase + y) * KPROJ + part * NOUT + c;
        for (int s = 0; s < SBR_N; ++s) {
            const f16x2* wrp = (const f16x2*)&wg[y][s * BPAD];
            float acc = 0.f;
            #pragma unroll
            for (int j = 0; j < BPAD / 2; ++j)
                acc = dot2f(xc[j], wrp[j], acc);
            orow[s * C_N] = (_Float16)acc;
        }
    }
}

// ---------------------------------------------------------------------------
// Combine: out[e,b,c] = sum_s wigner_inv[e,b,s] * 0.5*(h3[2eb,s,c] + h3[2eb+1,s,c])
// ---------------------------------------------------------------------------
__launch_bounds__(128)
__global__ void combine_kernel(const _Float16* __restrict__ h3, const float* __restrict__ wigner_inv,
                               float* __restrict__ out, int e0)
{
    __shared__ float ms[SBR_N * C_N];
    __shared__ float wv[SB_N * SBR_N];
    const int eb = blockIdx.x;
    const int e = e0 + eb;
    const int c = threadIdx.x;

    #pragma unroll
    for (int s = 0; s < SBR_N; ++s) {
        const float a = (float)h3[(size_t)(2 * eb) * NOUT + s * C_N + c];
        const float b = (float)h3[(size_t)(2 * eb + 1) * NOUT + s * C_N + c];
        ms[s * C_N + c] = 0.5f * (a + b);
    }
    for (int t = c; t < SB_N * SBR_N; t += 128)
        wv[t] = wigner_inv[(size_t)e * (SB_N * SBR_N) + t];
    __syncthreads();

    for (int b = 0; b < SB_N; ++b) {
        float acc = 0.f;
        #pragma unroll
        for (int s = 0; s < SBR_N; ++s)
            acc += wv[b * SBR_N + s] * ms[s * C_N + c];
        out[(size_t)e * (SB_N * C_N) + b * C_N + c] = acc;
    }
}

// ---------------------------------------------------------------------------
extern "C" void kernel_launch(void* const* d_in, const int* in_sizes, int n_in,
                              void* d_out, int out_size, void* d_ws, size_t ws_size,
                              hipStream_t stream)
{
    const float* x          = (const float*)d_in[0];
    const float* x_edge     = (const float*)d_in[1];
    const int*   eidx       = (const int*)d_in[2];
    const float* wigner     = (const float*)d_in[3];
    const float* wigner_inv = (const float*)d_in[4];
    const float* w_dist     = (const float*)d_in[5];
    const float* b_dist     = (const float*)d_in[6];
    const float* w_proj     = (const float*)d_in[7];
    const float* b_proj     = (const float*)d_in[8];
    const float* w_edge     = (const float*)d_in[9];
    const float* b_edge     = (const float*)d_in[10];
    const float* w_out      = (const float*)d_in[11];
    const float* b_out      = (const float*)d_in[12];
    float* out = (float*)d_out;

    // ---- workspace layout ----
    char* wsp = (char*)d_ws;
    auto alloc = [&](size_t bytes) -> char* {
        char* p = wsp;
        wsp += (bytes + 255) & ~(size_t)255;
        return p;
    };
    const int XE_ROWS = 10112;                       // 79*128, padded for staging reads
    _Float16* gate = (_Float16*)alloc((size_t)E_N * H_N * sizeof(_Float16));
    _Float16* wTd  = (_Float16*)alloc((size_t)H_N * NBF_N * sizeof(_Float16));
    _Float16* wTp  = (_Float16*)alloc((size_t)H_N * KPROJ * sizeof(_Float16));
    _Float16* wTe  = (_Float16*)alloc((size_t)H_N * H_N * sizeof(_Float16));
    _Float16* wTo  = (_Float16*)alloc((size_t)NOUT * H_N * sizeof(_Float16));
    _Float16* xeh  = (_Float16*)alloc((size_t)XE_ROWS * NBF_N * sizeof(_Float16));
    _Float16* xt   = (_Float16*)alloc((size_t)5000 * C_N * BPAD * sizeof(_Float16)); // 71.7 MB

    const size_t used = (size_t)(wsp - (char*)d_ws);
    const size_t avail = ws_size > used ? ws_size - used : 0;
    // per EY-row: rot (4864 f16) + h1 (256 f16) + h2 (256 f16) + KSPLIT partials (256 f32)
    const size_t per_row = (size_t)(KPROJ + H_N + H_N) * sizeof(_Float16)
                         + (size_t)KSPLIT * H_N * sizeof(float);            // 14848 B
    long cimax = (long)(avail / per_row) & ~127L;    // multiple of 128
    if (cimax > 20096) cimax = 20096;
    if (cimax < 128) cimax = 128;

    _Float16* rot  = (_Float16*)alloc((size_t)cimax * KPROJ * sizeof(_Float16)); // reused as h3
    _Float16* h1   = (_Float16*)alloc((size_t)cimax * H_N * sizeof(_Float16));
    _Float16* h2   = (_Float16*)alloc((size_t)cimax * H_N * sizeof(_Float16));
    float*    part = (float*)alloc((size_t)KSPLIT * cimax * H_N * sizeof(float));
    const size_t pstride = (size_t)cimax * H_N;      // f32 elements per split slice

    // ---- one-time prep ----
    transpose_to_f16<<<dim3(NBF_N / 32, H_N / 32), 256, 0, stream>>>(w_dist, wTd, NBF_N, H_N);
    transpose_to_f16<<<dim3(KPROJ / 32, H_N / 32), 256, 0, stream>>>(w_proj, wTp, KPROJ, H_N);
    transpose_to_f16<<<dim3(H_N / 32, H_N / 32), 256, 0, stream>>>(w_edge, wTe, H_N, H_N);
    transpose_to_f16<<<dim3(H_N / 32, NOUT / 32), 256, 0, stream>>>(w_out, wTo, H_N, NOUT);
    cvt_to_f16<<<dim3(1024), 256, 0, stream>>>(x_edge, xeh, (E_N * NBF_N) / 4);
    prep_xt<<<dim3(5000), 256, 0, stream>>>(x, xt);

    // 1. gate[e,h] = silu(x_edge @ w_dist + b_dist), fp16 out
    gemm_f16<0><<<dim3(H_N / 128, XE_ROWS / 128), 256, 0, stream>>>(
        xeh, NBF_N, wTd, b_dist, nullptr, gate, E_N, H_N, NBF_N, 0);

    for (long i0 = 0; i0 < 2L * E_N; i0 += cimax) {
        long ci = 2L * E_N - i0;
        if (ci > cimax) ci = cimax;
        const unsigned cb = (unsigned)((ci + 127) / 128);

        // 2. rotate source+target into rot[ci, 4864] (fp16), one block per edge
        rotate_v2<<<dim3((unsigned)(ci / 2)), 256, 0, stream>>>(
            xt, wigner, eidx, rot, (int)(i0 / 2));

        // 3a. split-K proj partials: part[ks] = rot[:, ks*KCH:+KCH] @ wTp^T
        gemm_f16_splitk<<<dim3(H_N / 128, cb, KSPLIT), 256, 0, stream>>>(
            rot, KPROJ, wTp, part, pstride, H_N);

        // 3b. h1 = silu(sum_ks part + b_proj) * gate[e]
        {
            const int total = (int)ci * (H_N / 4);
            unsigned rb = (unsigned)((total + 255) / 256);
            if (rb > 2048) rb = 2048;
            reduce_silu_gate<<<dim3(rb), 256, 0, stream>>>(
                part, pstride, b_proj, gate, h1, (int)ci, (int)i0);
        }

        // 4. h2 = silu(h1 @ w_edge + b_edge)
        gemm_f16<0><<<dim3(H_N / 128, cb), 256, 0, stream>>>(
            h1, H_N, wTe, b_edge, nullptr, h2, (int)ci, H_N, H_N, 0);

        // 5. h3 = silu(h2 @ w_out + b_out)   (reuses rot buffer)
        gemm_f16<0><<<dim3(NOUT / 128, cb), 256, 0, stream>>>(
            h2, H_N, wTo, b_out, nullptr, rot, (int)ci, NOUT, H_N, 0);

        // 6. out[e] = wigner_inv[e] @ mean_Y(h3)
        combine_kernel<<<dim3((unsigned)(ci / 2)), 128, 0, stream>>>(
            rot, wigner_inv, out, (int)(i0 / 2));
    }
}

// Round 6
// 964.317 us; speedup vs baseline: 1.1219x; 1.0326x over previous
//
#include <hip/hip_runtime.h>

#define E_N   10000
#define SB_N  49
#define SBR_N 19
#define C_N   128
#define H_N   256
#define NBF_N 512
#define KPROJ 4864   // 2*SBR*C
#define NOUT  2432   // SBR*C
#define XB    64     // b-dim (49) padded to 64 fp16, slot-swizzled (8-f16 granules)
#define KSPLIT 4
#define KCH   (KPROJ / KSPLIT)   // 1216, 38 BK=32 steps

typedef _Float16 f16x8 __attribute__((ext_vector_type(8)));
typedef _Float16 f16x4 __attribute__((ext_vector_type(4)));
typedef _Float16 f16x2 __attribute__((ext_vector_type(2)));
typedef float    f32x4 __attribute__((ext_vector_type(4)));

__device__ __forceinline__ float silu_f(float v) { return v / (1.0f + __expf(-v)); }

#define GLOBAL_PTR(p) ((const __attribute__((address_space(1))) void*)(p))
#define LDS_PTR(p)    ((__attribute__((address_space(3))) void*)(p))

// ---------------------------------------------------------------------------
// Tiled transpose + fp32->fp16: out[n*K + k] = (f16) in[k*N + n]
// ---------------------------------------------------------------------------
__launch_bounds__(256)
__global__ void transpose_to_f16(const float* __restrict__ in, _Float16* __restrict__ out,
                                 int K, int N)
{
    __shared__ float tile[32][33];
    const int k0 = blockIdx.x * 32;
    const int n0 = blockIdx.y * 32;
    const int tx = threadIdx.x & 31;
    const int ty = threadIdx.x >> 5;
    #pragma unroll
    for (int i = ty; i < 32; i += 8)
        if (k0 + i < K && n0 + tx < N)
            tile[i][tx] = in[(size_t)(k0 + i) * N + (n0 + tx)];
    __syncthreads();
    #pragma unroll
    for (int i = ty; i < 32; i += 8)
        if (n0 + i < N && k0 + tx < K)
            out[(size_t)(n0 + i) * K + (k0 + tx)] = (_Float16)tile[tx][i];
}

// ---------------------------------------------------------------------------
// fp32 -> fp16 bulk convert
// ---------------------------------------------------------------------------
__launch_bounds__(256)
__global__ void cvt_to_f16(const float* __restrict__ in, _Float16* __restrict__ out, int n4)
{
    int i = blockIdx.x * blockDim.x + threadIdx.x;
    const int stride = gridDim.x * blockDim.x;
    for (; i < n4; i += stride) {
        const float4 v = ((const float4*)in)[i];
        f16x4 o; o[0] = (_Float16)v.x; o[1] = (_Float16)v.y; o[2] = (_Float16)v.z; o[3] = (_Float16)v.w;
        ((f16x4*)out)[i] = o;
    }
}

// ---------------------------------------------------------------------------
// Prep: xt[n][c][slot][j] = (f16) x[n][b][c] with b = (slot ^ (c&7))*8 + j,
// zero for b >= 49. The XOR pre-bakes the LDS bank swizzle into the global
// layout so rotate_v3 can stage with linear global_load_lds and read B-frags
// conflict-free (2-way). One block per node, 256 threads.
// ---------------------------------------------------------------------------
__launch_bounds__(256)
__global__ void prep_xt(const float* __restrict__ x, _Float16* __restrict__ xt)
{
    __shared__ float xs[SB_N * C_N];           // 6272 f32
    const int n = blockIdx.x;
    const int tid = threadIdx.x;
    for (int t = tid; t < (SB_N * C_N) / 4; t += 256)
        ((float4*)xs)[t] = ((const float4*)(x + (size_t)n * (SB_N * C_N)))[t];
    __syncthreads();
    for (int t = tid; t < C_N * 8; t += 256) {     // 1024 slot-tasks
        const int c = t >> 3;
        const int slot = t & 7;
        const int kbase = (slot ^ (c & 7)) * 8;
        f16x8 v;
        #pragma unroll
        for (int j = 0; j < 8; ++j) {
            const int b = kbase + j;
            v[j] = (b < SB_N) ? (_Float16)xs[b * C_N + c] : (_Float16)0.f;
        }
        *(f16x8*)(xt + (size_t)n * (C_N * XB) + c * XB + slot * 8) = v;
    }
}

// ---------------------------------------------------------------------------
// MFMA GEMM (round-2 structure): C[M,N](f16) = silu(A@BT^T + bias) [* gate]
// BM=BN=128, BK=32, 256 threads = 4 waves (2x2), 4x4 16x16x32 frags per wave.
// ---------------------------------------------------------------------------
template<int GATED>
__launch_bounds__(256, 2)
__global__ void gemm_f16(const _Float16* __restrict__ A, int lda,
                         const _Float16* __restrict__ BT,
                         const float* __restrict__ bias,
                         const _Float16* __restrict__ gate,
                         _Float16* __restrict__ C,
                         int M, int N, int K, int i0)
{
    __shared__ __align__(16) _Float16 As[4][128][8];
    __shared__ __align__(16) _Float16 Bs[4][128][8];
    const int tid  = threadIdx.x;
    const int lane = tid & 63;
    const int w    = tid >> 6;
    const int wr   = w >> 1;
    const int wc   = w & 1;
    const int n0   = blockIdx.x * 128;
    const int m0   = blockIdx.y * 128;

    const int r01 = tid & 127;
    const int ks0 = tid >> 7;
    const int ks1 = ks0 + 2;
    const _Float16* a0 = A  + (size_t)(m0 + r01) * lda + ks0 * 8;
    const _Float16* a1 = A  + (size_t)(m0 + r01) * lda + ks1 * 8;
    const _Float16* b0 = BT + (size_t)(n0 + r01) * K   + ks0 * 8;
    const _Float16* b1 = BT + (size_t)(n0 + r01) * K   + ks1 * 8;
    _Float16* sA0 = &As[0][0][0] + (size_t)tid * 8;
    _Float16* sA1 = sA0 + 2048;
    _Float16* sB0 = &Bs[0][0][0] + (size_t)tid * 8;
    _Float16* sB1 = sB0 + 2048;

    const int frow = lane & 15;
    const int fks  = lane >> 4;
    const _Float16* fA = &As[fks][wr * 64 + frow][0];
    const _Float16* fB = &Bs[fks][wc * 64 + frow][0];

    f32x4 acc[4][4] = {};

    for (int k0 = 0; k0 < K; k0 += 32) {
        __builtin_amdgcn_global_load_lds(GLOBAL_PTR(a0 + k0), LDS_PTR(sA0), 16, 0, 0);
        __builtin_amdgcn_global_load_lds(GLOBAL_PTR(a1 + k0), LDS_PTR(sA1), 16, 0, 0);
        __builtin_amdgcn_global_load_lds(GLOBAL_PTR(b0 + k0), LDS_PTR(sB0), 16, 0, 0);
        __builtin_amdgcn_global_load_lds(GLOBAL_PTR(b1 + k0), LDS_PTR(sB1), 16, 0, 0);
        __syncthreads();
        f16x8 af[4], bf[4];
        #pragma unroll
        for (int m = 0; m < 4; ++m) af[m] = *(const f16x8*)(fA + m * 16 * 8);
        #pragma unroll
        for (int n = 0; n < 4; ++n) bf[n] = *(const f16x8*)(fB + n * 16 * 8);
        #pragma unroll
        for (int m = 0; m < 4; ++m)
            #pragma unroll
            for (int n = 0; n < 4; ++n)
                acc[m][n] = __builtin_amdgcn_mfma_f32_16x16x32_f16(af[m], bf[n], acc[m][n], 0, 0, 0);
        __syncthreads();
    }

    #pragma unroll
    for (int m = 0; m < 4; ++m) {
        #pragma unroll
        for (int n = 0; n < 4; ++n) {
            const int gn = n0 + wc * 64 + n * 16 + (lane & 15);
            #pragma unroll
            for (int r = 0; r < 4; ++r) {
                const int gm = m0 + wr * 64 + m * 16 + (lane >> 4) * 4 + r;
                if (gm < M) {
                    float v = acc[m][n][r] + bias[gn];
                    v = silu_f(v);
                    if (GATED) v *= (float)gate[(size_t)((i0 + gm) >> 1) * H_N + gn];
                    C[(size_t)gm * N + gn] = (_Float16)v;
                }
            }
        }
    }
}

// ---------------------------------------------------------------------------
// Split-K MFMA GEMM for proj: partial[ks][m][n] = A[m, ks*KCH : (ks+1)*KCH] @ BT^T
// ---------------------------------------------------------------------------
__launch_bounds__(256, 2)
__global__ void gemm_f16_splitk(const _Float16* __restrict__ A, int lda,
                                const _Float16* __restrict__ BT,
                                float* __restrict__ partial, size_t pstride,
                                int N)
{
    __shared__ __align__(16) _Float16 As[4][128][8];
    __shared__ __align__(16) _Float16 Bs[4][128][8];
    const int tid  = threadIdx.x;
    const int lane = tid & 63;
    const int w    = tid >> 6;
    const int wr   = w >> 1;
    const int wc   = w & 1;
    const int n0   = blockIdx.x * 128;
    const int m0   = blockIdx.y * 128;
    const int kspl = blockIdx.z;

    const int r01 = tid & 127;
    const int ks0 = tid >> 7;
    const int ks1 = ks0 + 2;
    const _Float16* a0 = A  + (size_t)(m0 + r01) * lda + kspl * KCH + ks0 * 8;
    const _Float16* a1 = A  + (size_t)(m0 + r01) * lda + kspl * KCH + ks1 * 8;
    const _Float16* b0 = BT + (size_t)(n0 + r01) * KPROJ + kspl * KCH + ks0 * 8;
    const _Float16* b1 = BT + (size_t)(n0 + r01) * KPROJ + kspl * KCH + ks1 * 8;
    _Float16* sA0 = &As[0][0][0] + (size_t)tid * 8;
    _Float16* sA1 = sA0 + 2048;
    _Float16* sB0 = &Bs[0][0][0] + (size_t)tid * 8;
    _Float16* sB1 = sB0 + 2048;

    const int frow = lane & 15;
    const int fks  = lane >> 4;
    const _Float16* fA = &As[fks][wr * 64 + frow][0];
    const _Float16* fB = &Bs[fks][wc * 64 + frow][0];

    f32x4 acc[4][4] = {};

    for (int k0 = 0; k0 < KCH; k0 += 32) {
        __builtin_amdgcn_global_load_lds(GLOBAL_PTR(a0 + k0), LDS_PTR(sA0), 16, 0, 0);
        __builtin_amdgcn_global_load_lds(GLOBAL_PTR(a1 + k0), LDS_PTR(sA1), 16, 0, 0);
        __builtin_amdgcn_global_load_lds(GLOBAL_PTR(b0 + k0), LDS_PTR(sB0), 16, 0, 0);
        __builtin_amdgcn_global_load_lds(GLOBAL_PTR(b1 + k0), LDS_PTR(sB1), 16, 0, 0);
        __syncthreads();
        f16x8 af[4], bf[4];
        #pragma unroll
        for (int m = 0; m < 4; ++m) af[m] = *(const f16x8*)(fA + m * 16 * 8);
        #pragma unroll
        for (int n = 0; n < 4; ++n) bf[n] = *(const f16x8*)(fB + n * 16 * 8);
        #pragma unroll
        for (int m = 0; m < 4; ++m)
            #pragma unroll
            for (int n = 0; n < 4; ++n)
                acc[m][n] = __builtin_amdgcn_mfma_f32_16x16x32_f16(af[m], bf[n], acc[m][n], 0, 0, 0);
        __syncthreads();
    }

    float* pout = partial + (size_t)kspl * pstride;
    #pragma unroll
    for (int m = 0; m < 4; ++m) {
        #pragma unroll
        for (int n = 0; n < 4; ++n) {
            const int gn = n0 + wc * 64 + n * 16 + (lane & 15);
            #pragma unroll
            for (int r = 0; r < 4; ++r) {
                const int gm = m0 + wr * 64 + m * 16 + (lane >> 4) * 4 + r;
                pout[(size_t)gm * N + gn] = acc[m][n][r];
            }
        }
    }
}

// ---------------------------------------------------------------------------
// Reduce split-K partials: h1[m,n] = silu(sum_ks partial + bias[n]) * gate
// ---------------------------------------------------------------------------
__launch_bounds__(256)
__global__ void reduce_silu_gate(const float* __restrict__ partial, size_t pstride,
                                 const float* __restrict__ bias,
                                 const _Float16* __restrict__ gate,
                                 _Float16* __restrict__ h1, int ci, int i0)
{
    const int total = ci * (H_N / 4);
    const int gstride = gridDim.x * blockDim.x;
    for (int idx = blockIdx.x * blockDim.x + threadIdx.x; idx < total; idx += gstride) {
        const int m = idx >> 6;
        const int n = (idx & 63) * 4;
        const size_t off = (size_t)m * H_N + n;
        const float4 p0 = *(const float4*)(partial + 0 * pstride + off);
        const float4 p1 = *(const float4*)(partial + 1 * pstride + off);
        const float4 p2 = *(const float4*)(partial + 2 * pstride + off);
        const float4 p3 = *(const float4*)(partial + 3 * pstride + off);
        const float4 bi = *(const float4*)(bias + n);
        const f16x4 g = *(const f16x4*)(gate + (size_t)((i0 + m) >> 1) * H_N + n);
        f16x4 o;
        float v;
        v = p0.x + p1.x + p2.x + p3.x + bi.x; v = silu_f(v) * (float)g[0]; o[0] = (_Float16)v;
        v = p0.y + p1.y + p2.y + p3.y + bi.y; v = silu_f(v) * (float)g[1]; o[1] = (_Float16)v;
        v = p0.z + p1.z + p2.z + p3.z + bi.z; v = silu_f(v) * (float)g[2]; o[2] = (_Float16)v;
        v = p0.w + p1.w + p2.w + p3.w + bi.w; v = silu_f(v) * (float)g[3]; o[3] = (_Float16)v;
        *(f16x4*)(h1 + off) = o;
    }
}

// ---------------------------------------------------------------------------
// Rotate v3 (MFMA): one block per edge. Batched GEMM:
//   rot[(y,s), part*2432 + s*128 + c] = sum_b Wstack[y*19+s, b] * X[b, c]
// A = Wstack [38->48, 49->64] in LDS (slot-swizzled, f32->f16 in-stage).
// B = xt panels [c=128][k=64] staged linearly via global_load_lds (swizzle
// pre-baked in global layout by prep_xt). 4 waves: (part, n-half).
// ---------------------------------------------------------------------------
__launch_bounds__(256, 4)
__global__ void rotate_v3(const _Float16* __restrict__ xt, const float* __restrict__ wigner,
                          const int* __restrict__ eidx, _Float16* __restrict__ rot, int e0)
{
    __shared__ __align__(16) _Float16 xs[2][C_N][XB];   // 32 KB
    __shared__ __align__(16) _Float16 wg[48][XB];       // 6 KB, slot-swizzled
    const int tid = threadIdx.x;
    const int e = e0 + blockIdx.x;
    const int node0 = eidx[e];
    const int node1 = eidx[E_N + e];

    // issue panel stages first (overlap with wg zero+fill)
    const _Float16* p0 = xt + (size_t)node0 * (C_N * XB);
    const _Float16* p1 = xt + (size_t)node1 * (C_N * XB);
    _Float16* d0 = &xs[0][0][0] + tid * 8;
    _Float16* d1 = &xs[1][0][0] + tid * 8;
    #pragma unroll
    for (int ch = 0; ch < 4; ++ch) {
        __builtin_amdgcn_global_load_lds(GLOBAL_PTR(p0 + ch * 2048 + tid * 8), LDS_PTR(d0 + ch * 2048), 16, 0, 0);
        __builtin_amdgcn_global_load_lds(GLOBAL_PTR(p1 + ch * 2048 + tid * 8), LDS_PTR(d1 + ch * 2048), 16, 0, 0);
    }

    // zero wg (pad rows/cols), then fill with f32->f16 wigner (slot-swizzled)
    {
        f16x8 z = {};
        for (int t = tid; t < (48 * XB) / 8; t += 256)
            *(f16x8*)(&wg[0][0] + t * 8) = z;
    }
    __syncthreads();
    const float* wsrc = wigner + (size_t)(2 * e) * (SBR_N * SB_N);
    for (int t = tid; t < 2 * SBR_N * SB_N; t += 256) {
        const int y = (t >= SBR_N * SB_N);
        const int sb = t - y * (SBR_N * SB_N);
        const int s = sb / SB_N, b = sb - s * SB_N;
        const int row = y * SBR_N + s;
        const int idx = ((b >> 3) ^ (row & 7)) * 8 + (b & 7);
        wg[row][idx] = (_Float16)wsrc[t];
    }
    __syncthreads();   // drains vmcnt (panels) + lgkm (wg fill)

    const int lane = tid & 63;
    const int w = tid >> 6;
    const int part = w >> 1;            // 0/1
    const int nh = w & 1;               // n-half: c 0-63 / 64-127
    const int frow = lane & 15;
    const int fks = lane >> 4;

    // A-frags: wg[mt*16+frow][ (kt*4+fks)^(row&7) slot ]
    f16x8 af[3][2];
    #pragma unroll
    for (int mt = 0; mt < 3; ++mt) {
        const int row = mt * 16 + frow;
        #pragma unroll
        for (int kt = 0; kt < 2; ++kt) {
            const int slot = (kt * 4 + fks) ^ (row & 7);
            af[mt][kt] = *(const f16x8*)&wg[row][slot * 8];
        }
    }

    f32x4 acc[3][4] = {};
    #pragma unroll
    for (int nt = 0; nt < 4; ++nt) {
        const int n = nh * 64 + nt * 16 + frow;
        #pragma unroll
        for (int kt = 0; kt < 2; ++kt) {
            const int slot = (kt * 4 + fks) ^ (n & 7);
            const f16x8 bf = *(const f16x8*)&xs[part][n][slot * 8];
            #pragma unroll
            for (int mt = 0; mt < 3; ++mt)
                acc[mt][nt] = __builtin_amdgcn_mfma_f32_16x16x32_f16(af[mt][kt], bf, acc[mt][nt], 0, 0, 0);
        }
    }

    const size_t rowbase = 2 * (size_t)blockIdx.x;
    #pragma unroll
    for (int mt = 0; mt < 3; ++mt) {
        #pragma unroll
        for (int rr = 0; rr < 4; ++rr) {
            const int m = mt * 16 + (lane >> 4) * 4 + rr;
            if (m < 2 * SBR_N) {
                const int y = (m >= SBR_N);
                const int s = m - y * SBR_N;
                _Float16* orow = rot + (rowbase + y) * KPROJ + part * NOUT + s * C_N
                               + nh * 64 + (lane & 15);
                #pragma unroll
                for (int nt = 0; nt < 4; ++nt)
                    orow[nt * 16] = (_Float16)acc[mt][nt][rr];
            }
        }
    }
}

// ---------------------------------------------------------------------------
// Combine: out[e,b,c] = sum_s wigner_inv[e,b,s] * 0.5*(h3[2eb,s,c] + h3[2eb+1,s,c])
// ---------------------------------------------------------------------------
__launch_bounds__(128)
__global__ void combine_kernel(const _Float16* __restrict__ h3, const float* __restrict__ wigner_inv,
                               float* __restrict__ out, int e0)
{
    __shared__ float ms[SBR_N * C_N];
    __shared__ float wv[SB_N * SBR_N];
    const int eb = blockIdx.x;
    const int e = e0 + eb;
    const int c = threadIdx.x;

    #pragma unroll
    for (int s = 0; s < SBR_N; ++s) {
        const float a = (float)h3[(size_t)(2 * eb) * NOUT + s * C_N + c];
        const float b = (float)h3[(size_t)(2 * eb + 1) * NOUT + s * C_N + c];
        ms[s * C_N + c] = 0.5f * (a + b);
    }
    for (int t = c; t < SB_N * SBR_N; t += 128)
        wv[t] = wigner_inv[(size_t)e * (SB_N * SBR_N) + t];
    __syncthreads();

    for (int b = 0; b < SB_N; ++b) {
        float acc = 0.f;
        #pragma unroll
        for (int s = 0; s < SBR_N; ++s)
            acc += wv[b * SBR_N + s] * ms[s * C_N + c];
        out[(size_t)e * (SB_N * C_N) + b * C_N + c] = acc;
    }
}

// ---------------------------------------------------------------------------
extern "C" void kernel_launch(void* const* d_in, const int* in_sizes, int n_in,
                              void* d_out, int out_size, void* d_ws, size_t ws_size,
                              hipStream_t stream)
{
    const float* x          = (const float*)d_in[0];
    const float* x_edge     = (const float*)d_in[1];
    const int*   eidx       = (const int*)d_in[2];
    const float* wigner     = (const float*)d_in[3];
    const float* wigner_inv = (const float*)d_in[4];
    const float* w_dist     = (const float*)d_in[5];
    const float* b_dist     = (const float*)d_in[6];
    const float* w_proj     = (const float*)d_in[7];
    const float* b_proj     = (const float*)d_in[8];
    const float* w_edge     = (const float*)d_in[9];
    const float* b_edge     = (const float*)d_in[10];
    const float* w_out      = (const float*)d_in[11];
    const float* b_out      = (const float*)d_in[12];
    float* out = (float*)d_out;

    // ---- workspace layout ----
    char* wsp = (char*)d_ws;
    auto alloc = [&](size_t bytes) -> char* {
        char* p = wsp;
        wsp += (bytes + 255) & ~(size_t)255;
        return p;
    };
    const int XE_ROWS = 10112;                       // 79*128, padded for staging reads
    _Float16* gate = (_Float16*)alloc((size_t)E_N * H_N * sizeof(_Float16));
    _Float16* wTd  = (_Float16*)alloc((size_t)H_N * NBF_N * sizeof(_Float16));
    _Float16* wTp  = (_Float16*)alloc((size_t)H_N * KPROJ * sizeof(_Float16));
    _Float16* wTe  = (_Float16*)alloc((size_t)H_N * H_N * sizeof(_Float16));
    _Float16* wTo  = (_Float16*)alloc((size_t)NOUT * H_N * sizeof(_Float16));
    _Float16* xeh  = (_Float16*)alloc((size_t)XE_ROWS * NBF_N * sizeof(_Float16));
    _Float16* xt   = (_Float16*)alloc((size_t)5000 * C_N * XB * sizeof(_Float16)); // 82 MB

    const size_t used = (size_t)(wsp - (char*)d_ws);
    const size_t avail = ws_size > used ? ws_size - used : 0;
    // per EY-row: rot (4864 f16) + h1 (256 f16) + h2 (256 f16) + KSPLIT partials (256 f32)
    const size_t per_row = (size_t)(KPROJ + H_N + H_N) * sizeof(_Float16)
                         + (size_t)KSPLIT * H_N * sizeof(float);            // 14848 B
    long cimax = (long)(avail / per_row) & ~127L;    // multiple of 128
    if (cimax > 20096) cimax = 20096;
    if (cimax < 128) cimax = 128;

    _Float16* rot  = (_Float16*)alloc((size_t)cimax * KPROJ * sizeof(_Float16)); // reused as h3
    _Float16* h1   = (_Float16*)alloc((size_t)cimax * H_N * sizeof(_Float16));
    _Float16* h2   = (_Float16*)alloc((size_t)cimax * H_N * sizeof(_Float16));
    float*    part = (float*)alloc((size_t)KSPLIT * cimax * H_N * sizeof(float));
    const size_t pstride = (size_t)cimax * H_N;      // f32 elements per split slice

    // ---- one-time prep ----
    transpose_to_f16<<<dim3(NBF_N / 32, H_N / 32), 256, 0, stream>>>(w_dist, wTd, NBF_N, H_N);
    transpose_to_f16<<<dim3(KPROJ / 32, H_N / 32), 256, 0, stream>>>(w_proj, wTp, KPROJ, H_N);
    transpose_to_f16<<<dim3(H_N / 32, H_N / 32), 256, 0, stream>>>(w_edge, wTe, H_N, H_N);
    transpose_to_f16<<<dim3(H_N / 32, NOUT / 32), 256, 0, stream>>>(w_out, wTo, H_N, NOUT);
    cvt_to_f16<<<dim3(1024), 256, 0, stream>>>(x_edge, xeh, (E_N * NBF_N) / 4);
    prep_xt<<<dim3(5000), 256, 0, stream>>>(x, xt);

    // 1. gate[e,h] = silu(x_edge @ w_dist + b_dist), fp16 out
    gemm_f16<0><<<dim3(H_N / 128, XE_ROWS / 128), 256, 0, stream>>>(
        xeh, NBF_N, wTd, b_dist, nullptr, gate, E_N, H_N, NBF_N, 0);

    for (long i0 = 0; i0 < 2L * E_N; i0 += cimax) {
        long ci = 2L * E_N - i0;
        if (ci > cimax) ci = cimax;
        const unsigned cb = (unsigned)((ci + 127) / 128);

        // 2. rotate (MFMA) source+target into rot[ci, 4864] (fp16), one block per edge
        rotate_v3<<<dim3((unsigned)(ci / 2)), 256, 0, stream>>>(
            xt, wigner, eidx, rot, (int)(i0 / 2));

        // 3a. split-K proj partials: part[ks] = rot[:, ks*KCH:+KCH] @ wTp^T
        gemm_f16_splitk<<<dim3(H_N / 128, cb, KSPLIT), 256, 0, stream>>>(
            rot, KPROJ, wTp, part, pstride, H_N);

        // 3b. h1 = silu(sum_ks part + b_proj) * gate[e]
        {
            const int total = (int)ci * (H_N / 4);
            unsigned rb = (unsigned)((total + 255) / 256);
            if (rb > 2048) rb = 2048;
            reduce_silu_gate<<<dim3(rb), 256, 0, stream>>>(
                part, pstride, b_proj, gate, h1, (int)ci, (int)i0);
        }

        // 4. h2 = silu(h1 @ w_edge + b_edge)
        gemm_f16<0><<<dim3(H_N / 128, cb), 256, 0, stream>>>(
            h1, H_N, wTe, b_edge, nullptr, h2, (int)ci, H_N, H_N, 0);

        // 5. h3 = silu(h2 @ w_out + b_out)   (reuses rot buffer)
        gemm_f16<0><<<dim3(NOUT / 128, cb), 256, 0, stream>>>(
            h2, H_N, wTo, b_out, nullptr, rot, (int)ci, NOUT, H_N, 0);

        // 6. out[e] = wigner_inv[e] @ mean_Y(h3)
        combine_kernel<<<dim3((unsigned)(ci / 2)), 128, 0, stream>>>(
            rot, wigner_inv, out, (int)(i0 / 2));
    }
}

// Round 7
// 961.233 us; speedup vs baseline: 1.1255x; 1.0032x over previous
//
#include <hip/hip_runtime.h>

#define E_N   10000
#define SB_N  49
#define SBR_N 19
#define C_N   128
#define H_N   256
#define NBF_N 512
#define KPROJ 4864   // 2*SBR*C
#define NOUT  2432   // SBR*C
#define XB    64     // b-dim (49) padded to 64 fp16, slot-swizzled (8-f16 granules)
#define KSPLIT 4
#define KCH   (KPROJ / KSPLIT)   // 1216, 38 BK=32 steps

typedef _Float16 f16x8 __attribute__((ext_vector_type(8)));
typedef _Float16 f16x4 __attribute__((ext_vector_type(4)));
typedef _Float16 f16x2 __attribute__((ext_vector_type(2)));
typedef float    f32x4 __attribute__((ext_vector_type(4)));

__device__ __forceinline__ float silu_f(float v) { return v / (1.0f + __expf(-v)); }

#define GLOBAL_PTR(p) ((const __attribute__((address_space(1))) void*)(p))
#define LDS_PTR(p)    ((__attribute__((address_space(3))) void*)(p))

// ---------------------------------------------------------------------------
// Tiled transpose + fp32->fp16: out[n*K + k] = (f16) in[k*N + n]
// ---------------------------------------------------------------------------
__launch_bounds__(256)
__global__ void transpose_to_f16(const float* __restrict__ in, _Float16* __restrict__ out,
                                 int K, int N)
{
    __shared__ float tile[32][33];
    const int k0 = blockIdx.x * 32;
    const int n0 = blockIdx.y * 32;
    const int tx = threadIdx.x & 31;
    const int ty = threadIdx.x >> 5;
    #pragma unroll
    for (int i = ty; i < 32; i += 8)
        if (k0 + i < K && n0 + tx < N)
            tile[i][tx] = in[(size_t)(k0 + i) * N + (n0 + tx)];
    __syncthreads();
    #pragma unroll
    for (int i = ty; i < 32; i += 8)
        if (n0 + i < N && k0 + tx < K)
            out[(size_t)(n0 + i) * K + (k0 + tx)] = (_Float16)tile[tx][i];
}

// ---------------------------------------------------------------------------
// fp32 -> fp16 bulk convert
// ---------------------------------------------------------------------------
__launch_bounds__(256)
__global__ void cvt_to_f16(const float* __restrict__ in, _Float16* __restrict__ out, int n4)
{
    int i = blockIdx.x * blockDim.x + threadIdx.x;
    const int stride = gridDim.x * blockDim.x;
    for (; i < n4; i += stride) {
        const float4 v = ((const float4*)in)[i];
        f16x4 o; o[0] = (_Float16)v.x; o[1] = (_Float16)v.y; o[2] = (_Float16)v.z; o[3] = (_Float16)v.w;
        ((f16x4*)out)[i] = o;
    }
}

// ---------------------------------------------------------------------------
// Prep: xt[n][c][slot][j] = (f16) x[n][b][c] with b = (slot ^ (c&7))*8 + j,
// zero for b >= 49. One block per node, 256 threads.
// ---------------------------------------------------------------------------
__launch_bounds__(256)
__global__ void prep_xt(const float* __restrict__ x, _Float16* __restrict__ xt)
{
    __shared__ float xs[SB_N * C_N];           // 6272 f32
    const int n = blockIdx.x;
    const int tid = threadIdx.x;
    for (int t = tid; t < (SB_N * C_N) / 4; t += 256)
        ((float4*)xs)[t] = ((const float4*)(x + (size_t)n * (SB_N * C_N)))[t];
    __syncthreads();
    for (int t = tid; t < C_N * 8; t += 256) {     // 1024 slot-tasks
        const int c = t >> 3;
        const int slot = t & 7;
        const int kbase = (slot ^ (c & 7)) * 8;
        f16x8 v;
        #pragma unroll
        for (int j = 0; j < 8; ++j) {
            const int b = kbase + j;
            v[j] = (b < SB_N) ? (_Float16)xs[b * C_N + c] : (_Float16)0.f;
        }
        *(f16x8*)(xt + (size_t)n * (C_N * XB) + c * XB + slot * 8) = v;
    }
}

// ---------------------------------------------------------------------------
// Pipelined K-loop building blocks (3-buffer ring, depth-2 prefetch,
// counted vmcnt + raw s_barrier so prefetched global_load_lds stay in
// flight across barriers). Hazards:
//  - read-before-land: per-wave vmcnt(N) then barrier rendezvous
//  - overwrite-before-read: end barrier; ring distance 3 > depth 2
// ---------------------------------------------------------------------------
#define PIPE_STAGE(BUF, KOFF) do {                                                            \
    _Float16* sa_ = &As[BUF][0][0][0] + tid * 8;                                              \
    _Float16* sb_ = &Bs[BUF][0][0][0] + tid * 8;                                              \
    __builtin_amdgcn_global_load_lds(GLOBAL_PTR(a0 + (KOFF)), LDS_PTR(sa_),        16, 0, 0); \
    __builtin_amdgcn_global_load_lds(GLOBAL_PTR(a1 + (KOFF)), LDS_PTR(sa_ + 2048), 16, 0, 0); \
    __builtin_amdgcn_global_load_lds(GLOBAL_PTR(b0 + (KOFF)), LDS_PTR(sb_),        16, 0, 0); \
    __builtin_amdgcn_global_load_lds(GLOBAL_PTR(b1 + (KOFF)), LDS_PTR(sb_ + 2048), 16, 0, 0); \
} while (0)

#define PIPE_COMPUTE(BUF) do {                                                          \
    const _Float16* fA_ = &As[BUF][fks][wr * 64 + frow][0];                             \
    const _Float16* fB_ = &Bs[BUF][fks][wc * 64 + frow][0];                             \
    f16x8 af[4], bf[4];                                                                 \
    _Pragma("unroll")                                                                   \
    for (int m_ = 0; m_ < 4; ++m_) af[m_] = *(const f16x8*)(fA_ + m_ * 128);            \
    _Pragma("unroll")                                                                   \
    for (int n_ = 0; n_ < 4; ++n_) bf[n_] = *(const f16x8*)(fB_ + n_ * 128);            \
    _Pragma("unroll")                                                                   \
    for (int m_ = 0; m_ < 4; ++m_)                                                      \
        _Pragma("unroll")                                                               \
        for (int n_ = 0; n_ < 4; ++n_)                                                  \
            acc[m_][n_] = __builtin_amdgcn_mfma_f32_16x16x32_f16(af[m_], bf[n_], acc[m_][n_], 0, 0, 0); \
} while (0)

// nt = K/32 (>= 3). Prologue stages 0,1; iter t stages t+2 and computes t.
#define PIPE_KLOOP(NT, KSTRIDE) do {                                                    \
    PIPE_STAGE(0, 0);                                                                   \
    PIPE_STAGE(1, (KSTRIDE));                                                           \
    int cur_ = 0;                                                                       \
    int koff_ = 2 * (KSTRIDE);                                                          \
    for (int t_ = 0; t_ < (NT) - 2; ++t_) {                                             \
        const int fut_ = cur_ >= 1 ? cur_ - 1 : 2;   /* (cur+2)%3 */                    \
        PIPE_STAGE(fut_, koff_); koff_ += (KSTRIDE);                                    \
        asm volatile("s_waitcnt vmcnt(8)" ::: "memory");                                \
        __builtin_amdgcn_s_barrier();                                                   \
        __builtin_amdgcn_sched_barrier(0);                                              \
        PIPE_COMPUTE(cur_);                                                             \
        __builtin_amdgcn_s_barrier();                                                   \
        cur_ = cur_ < 2 ? cur_ + 1 : 0;                                                 \
    }                                                                                   \
    asm volatile("s_waitcnt vmcnt(4)" ::: "memory");                                    \
    __builtin_amdgcn_s_barrier();                                                       \
    __builtin_amdgcn_sched_barrier(0);                                                  \
    PIPE_COMPUTE(cur_);                                                                 \
    cur_ = cur_ < 2 ? cur_ + 1 : 0;                                                     \
    asm volatile("s_waitcnt vmcnt(0)" ::: "memory");                                    \
    __builtin_amdgcn_s_barrier();                                                       \
    __builtin_amdgcn_sched_barrier(0);                                                  \
    PIPE_COMPUTE(cur_);                                                                 \
} while (0)

// ---------------------------------------------------------------------------
// MFMA GEMM: C[M,N](f16) = silu(A@BT^T + bias) [* gate]
// BM=BN=128, BK=32, 256 threads = 4 waves (2x2), pipelined K-loop.
// ---------------------------------------------------------------------------
template<int GATED>
__launch_bounds__(256, 2)
__global__ void gemm_f16(const _Float16* __restrict__ A, int lda,
                         const _Float16* __restrict__ BT,
                         const float* __restrict__ bias,
                         const _Float16* __restrict__ gate,
                         _Float16* __restrict__ C,
                         int M, int N, int K, int i0)
{
    __shared__ __align__(16) _Float16 As[3][4][128][8];   // 24 KB
    __shared__ __align__(16) _Float16 Bs[3][4][128][8];   // 24 KB
    const int tid  = threadIdx.x;
    const int lane = tid & 63;
    const int w    = tid >> 6;
    const int wr   = w >> 1;
    const int wc   = w & 1;
    const int n0   = blockIdx.x * 128;
    const int m0   = blockIdx.y * 128;

    const int r01 = tid & 127;
    const int ks0 = tid >> 7;
    const int ks1 = ks0 + 2;
    const _Float16* a0 = A  + (size_t)(m0 + r01) * lda + ks0 * 8;
    const _Float16* a1 = A  + (size_t)(m0 + r01) * lda + ks1 * 8;
    const _Float16* b0 = BT + (size_t)(n0 + r01) * K   + ks0 * 8;
    const _Float16* b1 = BT + (size_t)(n0 + r01) * K   + ks1 * 8;

    const int frow = lane & 15;
    const int fks  = lane >> 4;

    f32x4 acc[4][4] = {};
    const int nt = K >> 5;
    PIPE_KLOOP(nt, 32);

    #pragma unroll
    for (int m = 0; m < 4; ++m) {
        #pragma unroll
        for (int n = 0; n < 4; ++n) {
            const int gn = n0 + wc * 64 + n * 16 + (lane & 15);
            #pragma unroll
            for (int r = 0; r < 4; ++r) {
                const int gm = m0 + wr * 64 + m * 16 + (lane >> 4) * 4 + r;
                if (gm < M) {
                    float v = acc[m][n][r] + bias[gn];
                    v = silu_f(v);
                    if (GATED) v *= (float)gate[(size_t)((i0 + gm) >> 1) * H_N + gn];
                    C[(size_t)gm * N + gn] = (_Float16)v;
                }
            }
        }
    }
}

// ---------------------------------------------------------------------------
// Split-K MFMA GEMM for proj: partial[ks][m][n] = A[m, ks*KCH:+KCH] @ BT^T
// Same pipelined structure; raw f32 output.
// ---------------------------------------------------------------------------
__launch_bounds__(256, 2)
__global__ void gemm_f16_splitk(const _Float16* __restrict__ A, int lda,
                                const _Float16* __restrict__ BT,
                                float* __restrict__ partial, size_t pstride,
                                int N)
{
    __shared__ __align__(16) _Float16 As[3][4][128][8];
    __shared__ __align__(16) _Float16 Bs[3][4][128][8];
    const int tid  = threadIdx.x;
    const int lane = tid & 63;
    const int w    = tid >> 6;
    const int wr   = w >> 1;
    const int wc   = w & 1;
    const int n0   = blockIdx.x * 128;
    const int m0   = blockIdx.y * 128;
    const int kspl = blockIdx.z;

    const int r01 = tid & 127;
    const int ks0 = tid >> 7;
    const int ks1 = ks0 + 2;
    const _Float16* a0 = A  + (size_t)(m0 + r01) * lda + kspl * KCH + ks0 * 8;
    const _Float16* a1 = A  + (size_t)(m0 + r01) * lda + kspl * KCH + ks1 * 8;
    const _Float16* b0 = BT + (size_t)(n0 + r01) * KPROJ + kspl * KCH + ks0 * 8;
    const _Float16* b1 = BT + (size_t)(n0 + r01) * KPROJ + kspl * KCH + ks1 * 8;

    const int frow = lane & 15;
    const int fks  = lane >> 4;

    f32x4 acc[4][4] = {};
    PIPE_KLOOP(KCH / 32, 32);

    float* pout = partial + (size_t)kspl * pstride;
    #pragma unroll
    for (int m = 0; m < 4; ++m) {
        #pragma unroll
        for (int n = 0; n < 4; ++n) {
            const int gn = n0 + wc * 64 + n * 16 + (lane & 15);
            #pragma unroll
            for (int r = 0; r < 4; ++r) {
                const int gm = m0 + wr * 64 + m * 16 + (lane >> 4) * 4 + r;
                pout[(size_t)gm * N + gn] = acc[m][n][r];
            }
        }
    }
}

// ---------------------------------------------------------------------------
// Reduce split-K partials: h1[m,n] = silu(sum_ks partial + bias[n]) * gate
// ---------------------------------------------------------------------------
__launch_bounds__(256)
__global__ void reduce_silu_gate(const float* __restrict__ partial, size_t pstride,
                                 const float* __restrict__ bias,
                                 const _Float16* __restrict__ gate,
                                 _Float16* __restrict__ h1, int ci, int i0)
{
    const int total = ci * (H_N / 4);
    const int gstride = gridDim.x * blockDim.x;
    for (int idx = blockIdx.x * blockDim.x + threadIdx.x; idx < total; idx += gstride) {
        const int m = idx >> 6;
        const int n = (idx & 63) * 4;
        const size_t off = (size_t)m * H_N + n;
        const float4 p0 = *(const float4*)(partial + 0 * pstride + off);
        const float4 p1 = *(const float4*)(partial + 1 * pstride + off);
        const float4 p2 = *(const float4*)(partial + 2 * pstride + off);
        const float4 p3 = *(const float4*)(partial + 3 * pstride + off);
        const float4 bi = *(const float4*)(bias + n);
        const f16x4 g = *(const f16x4*)(gate + (size_t)((i0 + m) >> 1) * H_N + n);
        f16x4 o;
        float v;
        v = p0.x + p1.x + p2.x + p3.x + bi.x; v = silu_f(v) * (float)g[0]; o[0] = (_Float16)v;
        v = p0.y + p1.y + p2.y + p3.y + bi.y; v = silu_f(v) * (float)g[1]; o[1] = (_Float16)v;
        v = p0.z + p1.z + p2.z + p3.z + bi.z; v = silu_f(v) * (float)g[2]; o[2] = (_Float16)v;
        v = p0.w + p1.w + p2.w + p3.w + bi.w; v = silu_f(v) * (float)g[3]; o[3] = (_Float16)v;
        *(f16x4*)(h1 + off) = o;
    }
}

// ---------------------------------------------------------------------------
// Rotate v3 (MFMA): one block per edge. Batched GEMM:
//   rot[(y,s), part*2432 + s*128 + c] = sum_b Wstack[y*19+s, b] * X[b, c]
// ---------------------------------------------------------------------------
__launch_bounds__(256, 4)
__global__ void rotate_v3(const _Float16* __restrict__ xt, const float* __restrict__ wigner,
                          const int* __restrict__ eidx, _Float16* __restrict__ rot, int e0)
{
    __shared__ __align__(16) _Float16 xs[2][C_N][XB];   // 32 KB
    __shared__ __align__(16) _Float16 wg[48][XB];       // 6 KB, slot-swizzled
    const int tid = threadIdx.x;
    const int e = e0 + blockIdx.x;
    const int node0 = eidx[e];
    const int node1 = eidx[E_N + e];

    const _Float16* p0 = xt + (size_t)node0 * (C_N * XB);
    const _Float16* p1 = xt + (size_t)node1 * (C_N * XB);
    _Float16* d0 = &xs[0][0][0] + tid * 8;
    _Float16* d1 = &xs[1][0][0] + tid * 8;
    #pragma unroll
    for (int ch = 0; ch < 4; ++ch) {
        __builtin_amdgcn_global_load_lds(GLOBAL_PTR(p0 + ch * 2048 + tid * 8), LDS_PTR(d0 + ch * 2048), 16, 0, 0);
        __builtin_amdgcn_global_load_lds(GLOBAL_PTR(p1 + ch * 2048 + tid * 8), LDS_PTR(d1 + ch * 2048), 16, 0, 0);
    }

    {
        f16x8 z = {};
        for (int t = tid; t < (48 * XB) / 8; t += 256)
            *(f16x8*)(&wg[0][0] + t * 8) = z;
    }
    __syncthreads();
    const float* wsrc = wigner + (size_t)(2 * e) * (SBR_N * SB_N);
    for (int t = tid; t < 2 * SBR_N * SB_N; t += 256) {
        const int y = (t >= SBR_N * SB_N);
        const int sb = t - y * (SBR_N * SB_N);
        const int s = sb / SB_N, b = sb - s * SB_N;
        const int row = y * SBR_N + s;
        const int idx = ((b >> 3) ^ (row & 7)) * 8 + (b & 7);
        wg[row][idx] = (_Float16)wsrc[t];
    }
    __syncthreads();   // drains vmcnt (panels) + lgkm (wg fill)

    const int lane = tid & 63;
    const int w = tid >> 6;
    const int part = w >> 1;
    const int nh = w & 1;
    const int frow = lane & 15;
    const int fks = lane >> 4;

    f16x8 af[3][2];
    #pragma unroll
    for (int mt = 0; mt < 3; ++mt) {
        const int row = mt * 16 + frow;
        #pragma unroll
        for (int kt = 0; kt < 2; ++kt) {
            const int slot = (kt * 4 + fks) ^ (row & 7);
            af[mt][kt] = *(const f16x8*)&wg[row][slot * 8];
        }
    }

    f32x4 acc[3][4] = {};
    #pragma unroll
    for (int nt = 0; nt < 4; ++nt) {
        const int n = nh * 64 + nt * 16 + frow;
        #pragma unroll
        for (int kt = 0; kt < 2; ++kt) {
            const int slot = (kt * 4 + fks) ^ (n & 7);
            const f16x8 bf = *(const f16x8*)&xs[part][n][slot * 8];
            #pragma unroll
            for (int mt = 0; mt < 3; ++mt)
                acc[mt][nt] = __builtin_amdgcn_mfma_f32_16x16x32_f16(af[mt][kt], bf, acc[mt][nt], 0, 0, 0);
        }
    }

    const size_t rowbase = 2 * (size_t)blockIdx.x;
    #pragma unroll
    for (int mt = 0; mt < 3; ++mt) {
        #pragma unroll
        for (int rr = 0; rr < 4; ++rr) {
            const int m = mt * 16 + (lane >> 4) * 4 + rr;
            if (m < 2 * SBR_N) {
                const int y = (m >= SBR_N);
                const int s = m - y * SBR_N;
                _Float16* orow = rot + (rowbase + y) * KPROJ + part * NOUT + s * C_N
                               + nh * 64 + (lane & 15);
                #pragma unroll
                for (int nt = 0; nt < 4; ++nt)
                    orow[nt * 16] = (_Float16)acc[mt][nt][rr];
            }
        }
    }
}

// ---------------------------------------------------------------------------
// Combine: out[e,b,c] = sum_s wigner_inv[e,b,s] * 0.5*(h3[2eb,s,c] + h3[2eb+1,s,c])
// ---------------------------------------------------------------------------
__launch_bounds__(128)
__global__ void combine_kernel(const _Float16* __restrict__ h3, const float* __restrict__ wigner_inv,
                               float* __restrict__ out, int e0)
{
    __shared__ float ms[SBR_N * C_N];
    __shared__ float wv[SB_N * SBR_N];
    const int eb = blockIdx.x;
    const int e = e0 + eb;
    const int c = threadIdx.x;

    #pragma unroll
    for (int s = 0; s < SBR_N; ++s) {
        const float a = (float)h3[(size_t)(2 * eb) * NOUT + s * C_N + c];
        const float b = (float)h3[(size_t)(2 * eb + 1) * NOUT + s * C_N + c];
        ms[s * C_N + c] = 0.5f * (a + b);
    }
    for (int t = c; t < SB_N * SBR_N; t += 128)
        wv[t] = wigner_inv[(size_t)e * (SB_N * SBR_N) + t];
    __syncthreads();

    for (int b = 0; b < SB_N; ++b) {
        float acc = 0.f;
        #pragma unroll
        for (int s = 0; s < SBR_N; ++s)
            acc += wv[b * SBR_N + s] * ms[s * C_N + c];
        out[(size_t)e * (SB_N * C_N) + b * C_N + c] = acc;
    }
}

// ---------------------------------------------------------------------------
extern "C" void kernel_launch(void* const* d_in, const int* in_sizes, int n_in,
                              void* d_out, int out_size, void* d_ws, size_t ws_size,
                              hipStream_t stream)
{
    const float* x          = (const float*)d_in[0];
    const float* x_edge     = (const float*)d_in[1];
    const int*   eidx       = (const int*)d_in[2];
    const float* wigner     = (const float*)d_in[3];
    const float* wigner_inv = (const float*)d_in[4];
    const float* w_dist     = (const float*)d_in[5];
    const float* b_dist     = (const float*)d_in[6];
    const float* w_proj     = (const float*)d_in[7];
    const float* b_proj     = (const float*)d_in[8];
    const float* w_edge     = (const float*)d_in[9];
    const float* b_edge     = (const float*)d_in[10];
    const float* w_out      = (const float*)d_in[11];
    const float* b_out      = (const float*)d_in[12];
    float* out = (float*)d_out;

    // ---- workspace layout ----
    char* wsp = (char*)d_ws;
    auto alloc = [&](size_t bytes) -> char* {
        char* p = wsp;
        wsp += (bytes + 255) & ~(size_t)255;
        return p;
    };
    const int XE_ROWS = 10112;                       // 79*128, padded for staging reads
    _Float16* gate = (_Float16*)alloc((size_t)E_N * H_N * sizeof(_Float16));
    _Float16* wTd  = (_Float16*)alloc((size_t)H_N * NBF_N * sizeof(_Float16));
    _Float16* wTp  = (_Float16*)alloc((size_t)H_N * KPROJ * sizeof(_Float16));
    _Float16* wTe  = (_Float16*)alloc((size_t)H_N * H_N * sizeof(_Float16));
    _Float16* wTo  = (_Float16*)alloc((size_t)NOUT * H_N * sizeof(_Float16));
    _Float16* xeh  = (_Float16*)alloc((size_t)XE_ROWS * NBF_N * sizeof(_Float16));
    _Float16* xt   = (_Float16*)alloc((size_t)5000 * C_N * XB * sizeof(_Float16)); // 82 MB

    const size_t used = (size_t)(wsp - (char*)d_ws);
    const size_t avail = ws_size > used ? ws_size - used : 0;
    const size_t per_row = (size_t)(KPROJ + H_N + H_N) * sizeof(_Float16)
                         + (size_t)KSPLIT * H_N * sizeof(float);            // 14848 B
    long cimax = (long)(avail / per_row) & ~127L;    // multiple of 128
    if (cimax > 20096) cimax = 20096;
    if (cimax < 128) cimax = 128;

    _Float16* rot  = (_Float16*)alloc((size_t)cimax * KPROJ * sizeof(_Float16)); // reused as h3
    _Float16* h1   = (_Float16*)alloc((size_t)cimax * H_N * sizeof(_Float16));
    _Float16* h2   = (_Float16*)alloc((size_t)cimax * H_N * sizeof(_Float16));
    float*    part = (float*)alloc((size_t)KSPLIT * cimax * H_N * sizeof(float));
    const size_t pstride = (size_t)cimax * H_N;

    // ---- one-time prep ----
    transpose_to_f16<<<dim3(NBF_N / 32, H_N / 32), 256, 0, stream>>>(w_dist, wTd, NBF_N, H_N);
    transpose_to_f16<<<dim3(KPROJ / 32, H_N / 32), 256, 0, stream>>>(w_proj, wTp, KPROJ, H_N);
    transpose_to_f16<<<dim3(H_N / 32, H_N / 32), 256, 0, stream>>>(w_edge, wTe, H_N, H_N);
    transpose_to_f16<<<dim3(H_N / 32, NOUT / 32), 256, 0, stream>>>(w_out, wTo, H_N, NOUT);
    cvt_to_f16<<<dim3(1024), 256, 0, stream>>>(x_edge, xeh, (E_N * NBF_N) / 4);
    prep_xt<<<dim3(5000), 256, 0, stream>>>(x, xt);

    // 1. gate[e,h] = silu(x_edge @ w_dist + b_dist), fp16 out
    gemm_f16<0><<<dim3(H_N / 128, XE_ROWS / 128), 256, 0, stream>>>(
        xeh, NBF_N, wTd, b_dist, nullptr, gate, E_N, H_N, NBF_N, 0);

    for (long i0 = 0; i0 < 2L * E_N; i0 += cimax) {
        long ci = 2L * E_N - i0;
        if (ci > cimax) ci = cimax;
        const unsigned cb = (unsigned)((ci + 127) / 128);

        // 2. rotate (MFMA) source+target into rot[ci, 4864] (fp16), one block per edge
        rotate_v3<<<dim3((unsigned)(ci / 2)), 256, 0, stream>>>(
            xt, wigner, eidx, rot, (int)(i0 / 2));

        // 3a. split-K proj partials: part[ks] = rot[:, ks*KCH:+KCH] @ wTp^T
        gemm_f16_splitk<<<dim3(H_N / 128, cb, KSPLIT), 256, 0, stream>>>(
            rot, KPROJ, wTp, part, pstride, H_N);

        // 3b. h1 = silu(sum_ks part + b_proj) * gate[e]
        {
            const int total = (int)ci * (H_N / 4);
            unsigned rb = (unsigned)((total + 255) / 256);
            if (rb > 2048) rb = 2048;
            reduce_silu_gate<<<dim3(rb), 256, 0, stream>>>(
                part, pstride, b_proj, gate, h1, (int)ci, (int)i0);
        }

        // 4. h2 = silu(h1 @ w_edge + b_edge)
        gemm_f16<0><<<dim3(H_N / 128, cb), 256, 0, stream>>>(
            h1, H_N, wTe, b_edge, nullptr, h2, (int)ci, H_N, H_N, 0);

        // 5. h3 = silu(h2 @ w_out + b_out)   (reuses rot buffer)
        gemm_f16<0><<<dim3(NOUT / 128, cb), 256, 0, stream>>>(
            h2, H_N, wTo, b_out, nullptr, rot, (int)ci, NOUT, H_N, 0);

        // 6. out[e] = wigner_inv[e] @ mean_Y(h3)
        combine_kernel<<<dim3((unsigned)(ci / 2)), 128, 0, stream>>>(
            rot, wigner_inv, out, (int)(i0 / 2));
    }
}